// Round 22
// baseline (116.033 us; speedup 1.0000x reference)
//
#include <hip/hip_runtime.h>
#include <hip/hip_fp16.h>
#include <cstdint>

#define IN_F   4096
#define OUT_F  4096
#define BS     64      // sparsity block size
#define NB     64      // blocks per weight dim
#define N_TOK  8192
#define TM     256     // token tile per workgroup (4 waves x 64 rows)
#define NMT    (N_TOK / TM)   // 32 token tiles

typedef __attribute__((ext_vector_type(8))) _Float16       f16x8;
typedef __attribute__((ext_vector_type(8))) unsigned short u16x8;
typedef __attribute__((ext_vector_type(4))) float          f32x4;

// wave-uniform ballot of the block-constant mask row `br`
__device__ __forceinline__ unsigned long long mask_ballot(
        const float* __restrict__ mask, int br, int lane) {
    float mv = mask[(size_t)(br * BS) * IN_F + (size_t)lane * BS];
    return __ballot(mv != 0.0f);
}

// pack 8 fp32 -> 8 fp16 (RNE) bit patterns
__device__ __forceinline__ u16x8 pack8(f32x4 a, f32x4 b) {
    u16x8 o;
#pragma unroll
    for (int j = 0; j < 4; ++j) o[j]     = __half_as_ushort(__float2half_rn(a[j]));
#pragma unroll
    for (int j = 0; j < 4; ++j) o[4 + j] = __half_as_ushort(__float2half_rn(b[j]));
    return o;
}

// ---------------------------------------------------------------------------
// Single fused block-sparse GEMM: out = x @ (W o mask)^T + bias.
// fp16 MFMA, fp32 accumulate, no workspace. A and B reg-loaded as fp32,
// converted fp16, ds_written XOR-swizzled (r21 structure) with TWO fixes:
//  (1) sched_barrier(0) after the load-issue block: r21's VGPR=108 proved
//      the compiler sank the 20 batched loads into the commit lambdas,
//      serializing them into 8 dependent ~550cy chains (11K cy/iter — the
//      whole 118us). The barrier pins issue-before-MFMA; latency then hides
//      under MFMA + ds_reads and commit finds data landed.
//  (2) nontemporal out-stores: keep the 132 MB write stream from evicting
//      the phase's 4 MB x-slab (r21 FETCH 285 MB ~= 2x compulsory).
// XCD 1-mt phases: 64 co-resident WGs of (xcd,phase) share one mt's 4 MB
// fp32 x-slab = one XCD L2; W unique 6.7 MB L3-resident.
// ---------------------------------------------------------------------------
__global__ __launch_bounds__(256, 2)
void bsr_fused5_kernel(const float* __restrict__ x,
                       const float* __restrict__ w,
                       const float* __restrict__ bias,
                       const float* __restrict__ mask,
                       float* __restrict__ out) {
    __shared__ unsigned short xs[2][TM * BS];   // 2 x 32 KB fp16 A tile
    __shared__ unsigned short wsb[2][BS * BS];  // 2 x  8 KB fp16 W tile

    const int b     = blockIdx.x;     // 0..2047
    const int xcd   = b & 7;
    const int j     = b >> 3;         // 0..255
    const int phase = j >> 6;         // 0..3  (1-mt phase: 4MB fp32 slab = L2)
    const int br    = j & 63;         // br-fast within phase
    const int mt    = xcd * 4 + phase;

    const int tid  = threadIdx.x;
    const int lane = tid & 63;
    const int wv   = tid >> 6;        // wave 0..3 -> rows [wv*64, wv*64+64)
    const int fr   = lane & 15;
    const int kg   = lane >> 4;

    const int mbase = mt * TM;
    const int obase = br * BS;

    unsigned long long ball = mask_ballot(mask, br, lane);
    const int cnt = __popcll(ball);

    f32x4 acc[4][4];
#pragma unroll
    for (int a = 0; a < 4; ++a)
#pragma unroll
        for (int c = 0; c < 4; ++c) acc[a][c] = (f32x4)0.0f;

    // ---- A: reg-load fp32 x tile (256x64), convert+swizzled ds_write ----
    f32x4 rA[8][2];
    auto loadA = [&](int kb) {
#pragma unroll
        for (int l = 0; l < 8; ++l) {
            int g = tid + l * 256, row = g >> 3, slot = g & 7;
            const f32x4* src = (const f32x4*)(x + (size_t)(mbase + row) * IN_F
                                              + kb * BS + slot * 8);
            rA[l][0] = src[0];
            rA[l][1] = src[1];
        }
    };
    auto commitA = [&](int bb) {
#pragma unroll
        for (int l = 0; l < 8; ++l) {
            int g = tid + l * 256, row = g >> 3, slot = g & 7;
            *(u16x8*)&xs[bb][row * 64 + ((slot ^ (row & 7)) << 3)]
                = pack8(rA[l][0], rA[l][1]);
        }
    };
    // ---- W: reg-load fp32 (64x64), convert+swizzled ds_write ----
    f32x4 rW[2][2];
    auto loadW = [&](int kb) {
#pragma unroll
        for (int l = 0; l < 2; ++l) {
            int g = tid + l * 256, row = g >> 3, slot = g & 7;
            const f32x4* src = (const f32x4*)(w + (size_t)(obase + row) * IN_F
                                              + kb * BS + slot * 8);
            rW[l][0] = src[0];
            rW[l][1] = src[1];
        }
    };
    auto commitW = [&](int bb) {
#pragma unroll
        for (int l = 0; l < 2; ++l) {
            int g = tid + l * 256, row = g >> 3, slot = g & 7;
            *(u16x8*)&wsb[bb][row * 64 + ((slot ^ (row & 7)) << 3)]
                = pack8(rW[l][0], rW[l][1]);
        }
    };

    unsigned long long rem = ball;
    int cur = 0;
    if (cnt > 0) {
        int kb0 = __ffsll(rem) - 1;
        rem &= rem - 1;
        loadA(kb0);
        loadW(kb0);
        commitA(0);             // waits its loads via data dep
        commitW(0);
    }
    __syncthreads();

    for (int si = 0; si < cnt; ++si) {
        const bool more = (si + 1 < cnt);
        if (more) {                          // T14: issue next-tile loads early
            int kbn = __ffsll(rem) - 1;
            rem &= rem - 1;
            loadA(kbn);
            loadW(kbn);
        }
        // Pin: everything above (the 20 load issues) must be EMITTED above;
        // prevents the scheduler sinking loads into the commit lambdas
        // (r21: VGPR=108 -> serialized chains -> 118us).
        __builtin_amdgcn_sched_barrier(0);

#pragma unroll
        for (int ks = 0; ks < 2; ++ks) {
            f16x8 a[4], bfr[4];
#pragma unroll
            for (int mr = 0; mr < 4; ++mr) {
                int row = wv * 64 + mr * 16 + fr;
                a[mr] = *(const f16x8*)&xs[cur][row * 64 + (((ks * 4 + kg) ^ (row & 7)) << 3)];
            }
#pragma unroll
            for (int nr = 0; nr < 4; ++nr) {
                int row = nr * 16 + fr;
                bfr[nr] = *(const f16x8*)&wsb[cur][row * 64 + (((ks * 4 + kg) ^ (row & 7)) << 3)];
            }
#pragma unroll
            for (int mr = 0; mr < 4; ++mr)
#pragma unroll
                for (int nr = 0; nr < 4; ++nr)
                    acc[mr][nr] = __builtin_amdgcn_mfma_f32_16x16x32_f16(
                        a[mr], bfr[nr], acc[mr][nr], 0, 0, 0);
        }
        if (more) {                          // T14: commit late (loads landed)
            commitA(cur ^ 1);
            commitW(cur ^ 1);
        }
        __syncthreads();                     // all reads of cur done; next ready
        cur ^= 1;
    }

    // ---- epilogue: bias + NONTEMPORAL fp32 stores (protect L2 x-slab).
    // C/D layout: col = lane&15 (fr), row = kg*4 + r.
#pragma unroll
    for (int nr = 0; nr < 4; ++nr) {
        float bv = bias[obase + nr * 16 + fr];
#pragma unroll
        for (int mr = 0; mr < 4; ++mr) {
#pragma unroll
            for (int r = 0; r < 4; ++r) {
                int m = mbase + wv * 64 + mr * 16 + kg * 4 + r;
                __builtin_nontemporal_store(acc[mr][nr][r] + bv,
                    &out[(size_t)m * OUT_F + obase + nr * 16 + fr]);
            }
        }
    }
}

extern "C" void kernel_launch(void* const* d_in, const int* in_sizes, int n_in,
                              void* d_out, int out_size, void* d_ws, size_t ws_size,
                              hipStream_t stream) {
    const float* x    = (const float*)d_in[0];
    const float* w    = (const float*)d_in[1];
    const float* bias = (const float*)d_in[2];
    const float* mask = (const float*)d_in[3];
    float* out = (float*)d_out;

    bsr_fused5_kernel<<<NMT * NB, 256, 0, stream>>>(x, w, bias, mask, out);
}

// Round 23
// 113.590 us; speedup vs baseline: 1.0215x; 1.0215x over previous
//
#include <hip/hip_runtime.h>
#include <hip/hip_fp16.h>
#include <cstdint>

#define IN_F   4096
#define OUT_F  4096
#define BS     64      // sparsity block size
#define NB     64      // blocks per weight dim
#define N_TOK  8192
#define TM     256     // token tile per workgroup (8 waves x 32 rows)
#define NMT    (N_TOK / TM)   // 32 token tiles

typedef __attribute__((ext_vector_type(8))) _Float16       f16x8;
typedef __attribute__((ext_vector_type(8))) unsigned short u16x8;
typedef __attribute__((ext_vector_type(4))) float          f32x4;

// wave-uniform ballot of the block-constant mask row `br`
__device__ __forceinline__ unsigned long long mask_ballot(
        const float* __restrict__ mask, int br, int lane) {
    float mv = mask[(size_t)(br * BS) * IN_F + (size_t)lane * BS];
    return __ballot(mv != 0.0f);
}

// pack 8 fp32 -> 8 fp16 (RNE) bit patterns
__device__ __forceinline__ u16x8 pack8(f32x4 a, f32x4 b) {
    u16x8 o;
#pragma unroll
    for (int j = 0; j < 4; ++j) o[j]     = __half_as_ushort(__float2half_rn(a[j]));
#pragma unroll
    for (int j = 0; j < 4; ++j) o[4 + j] = __half_as_ushort(__float2half_rn(b[j]));
    return o;
}

// ---------------------------------------------------------------------------
// Single fused block-sparse GEMM: out = x @ (W o mask)^T + bias.
// fp16 MFMA, fp32 accumulate, no workspace. r21 structure re-balanced for
// REGISTER PRESSURE + OCCUPANCY (r21/r22 post-mortem: VGPR=108 proved the
// 64-VGPR load batch could not coexist with acc[4][4]=64; loads serialized
// into ~550cy dependent chains = the whole 118us):
//   - 512 threads/WG (8 waves x 32-row tiles): acc 32 + rA 32 + rW 8 VGPRs
//     -> batch fits under the 128-VGPR cap of __launch_bounds__(512,4).
//   - 2 WG/CU x 8 waves = 16 waves/CU capacity (2x r21) to hide latency.
// T14 split: loads for si+1 issued before compute(si), commits after.
// XCD 1-mt phases: 64 co-resident WGs share one mt's 4 MB fp32 x-slab = one
// XCD L2; W unique kept blocks 6.7 MB L3-resident. Plain stores (r22:
// nontemporal caused 64B-segment RMW amplification, WRITE 132->180 MB).
// ---------------------------------------------------------------------------
__global__ __launch_bounds__(512, 4)
void bsr_fused6_kernel(const float* __restrict__ x,
                       const float* __restrict__ w,
                       const float* __restrict__ bias,
                       const float* __restrict__ mask,
                       float* __restrict__ out) {
    __shared__ unsigned short xs[2][TM * BS];   // 2 x 32 KB fp16 A tile
    __shared__ unsigned short wsb[2][BS * BS];  // 2 x  8 KB fp16 W tile

    const int b     = blockIdx.x;     // 0..2047
    const int xcd   = b & 7;
    const int j     = b >> 3;         // 0..255
    const int phase = j >> 6;         // 0..3  (1-mt phase: 4MB fp32 slab = L2)
    const int br    = j & 63;         // br-fast within phase
    const int mt    = xcd * 4 + phase;

    const int tid  = threadIdx.x;     // 0..511
    const int lane = tid & 63;
    const int wv   = tid >> 6;        // wave 0..7 -> rows [wv*32, wv*32+32)
    const int fr   = lane & 15;
    const int kg   = lane >> 4;

    const int mbase = mt * TM;
    const int obase = br * BS;

    unsigned long long ball = mask_ballot(mask, br, lane);
    const int cnt = __popcll(ball);

    f32x4 acc[2][4];
#pragma unroll
    for (int a = 0; a < 2; ++a)
#pragma unroll
        for (int c = 0; c < 4; ++c) acc[a][c] = (f32x4)0.0f;

    // ---- A: reg-load fp32 x tile (256x64): 4 pairs/thread ----
    // g = tid + l*512: row = g>>3 (0..255), slot = g&7. Wave instruction
    // touches 8 rows x 256B contiguous.
    f32x4 rA[4][2];
    auto loadA = [&](int kb) {
#pragma unroll
        for (int l = 0; l < 4; ++l) {
            int g = tid + l * 512, row = g >> 3, slot = g & 7;
            const f32x4* src = (const f32x4*)(x + (size_t)(mbase + row) * IN_F
                                              + kb * BS + slot * 8);
            rA[l][0] = src[0];
            rA[l][1] = src[1];
        }
    };
    auto commitA = [&](int bb) {
#pragma unroll
        for (int l = 0; l < 4; ++l) {
            int g = tid + l * 512, row = g >> 3, slot = g & 7;
            *(u16x8*)&xs[bb][row * 64 + ((slot ^ (row & 7)) << 3)]
                = pack8(rA[l][0], rA[l][1]);
        }
    };
    // ---- W: reg-load fp32 (64x64): 1 pair/thread ----
    f32x4 rW[2];
    auto loadW = [&](int kb) {
        int row = tid >> 3, slot = tid & 7;
        const f32x4* src = (const f32x4*)(w + (size_t)(obase + row) * IN_F
                                          + kb * BS + slot * 8);
        rW[0] = src[0];
        rW[1] = src[1];
    };
    auto commitW = [&](int bb) {
        int row = tid >> 3, slot = tid & 7;
        *(u16x8*)&wsb[bb][row * 64 + ((slot ^ (row & 7)) << 3)]
            = pack8(rW[0], rW[1]);
    };

    unsigned long long rem = ball;
    int cur = 0;
    if (cnt > 0) {
        int kb0 = __ffsll(rem) - 1;
        rem &= rem - 1;
        loadA(kb0);
        loadW(kb0);
        commitA(0);             // waits its loads via data dep
        commitW(0);
    }
    __syncthreads();

    for (int si = 0; si < cnt; ++si) {
        const bool more = (si + 1 < cnt);
        if (more) {                          // T14: issue next-tile loads early
            int kbn = __ffsll(rem) - 1;
            rem &= rem - 1;
            loadA(kbn);
            loadW(kbn);
        }

#pragma unroll
        for (int ks = 0; ks < 2; ++ks) {
            f16x8 a[2], bfr[4];
#pragma unroll
            for (int mr = 0; mr < 2; ++mr) {
                int row = wv * 32 + mr * 16 + fr;
                a[mr] = *(const f16x8*)&xs[cur][row * 64 + (((ks * 4 + kg) ^ (row & 7)) << 3)];
            }
#pragma unroll
            for (int nr = 0; nr < 4; ++nr) {
                int row = nr * 16 + fr;
                bfr[nr] = *(const f16x8*)&wsb[cur][row * 64 + (((ks * 4 + kg) ^ (row & 7)) << 3)];
            }
#pragma unroll
            for (int mr = 0; mr < 2; ++mr)
#pragma unroll
                for (int nr = 0; nr < 4; ++nr)
                    acc[mr][nr] = __builtin_amdgcn_mfma_f32_16x16x32_f16(
                        a[mr], bfr[nr], acc[mr][nr], 0, 0, 0);
        }
        if (more) {                          // T14: commit late (loads landed)
            commitA(cur ^ 1);
            commitW(cur ^ 1);
        }
        __syncthreads();                     // all reads of cur done; next ready
        cur ^= 1;
    }

    // ---- epilogue: bias + fp32 stores. C/D: col=lane&15, row=(lane>>4)*4+r ----
#pragma unroll
    for (int nr = 0; nr < 4; ++nr) {
        float bv = bias[obase + nr * 16 + fr];
#pragma unroll
        for (int mr = 0; mr < 2; ++mr) {
#pragma unroll
            for (int r = 0; r < 4; ++r) {
                int m = mbase + wv * 32 + mr * 16 + kg * 4 + r;
                out[(size_t)m * OUT_F + obase + nr * 16 + fr] = acc[mr][nr][r] + bv;
            }
        }
    }
}

extern "C" void kernel_launch(void* const* d_in, const int* in_sizes, int n_in,
                              void* d_out, int out_size, void* d_ws, size_t ws_size,
                              hipStream_t stream) {
    const float* x    = (const float*)d_in[0];
    const float* w    = (const float*)d_in[1];
    const float* bias = (const float*)d_in[2];
    const float* mask = (const float*)d_in[3];
    float* out = (float*)d_out;

    bsr_fused6_kernel<<<NMT * NB, 512, 0, stream>>>(x, w, bias, mask, out);
}